// Round 1
// baseline (2280.972 us; speedup 1.0000x reference)
//
#include <hip/hip_runtime.h>

// Encoder: embed -> 4x input GEMM (bf16 MFMA) -> 4x LSTM scan (MFMA, batch-split)
//          -> co-attention + output head.
// Sizes: V=100000 E=300 H=256 OUT=3 B=128 LS=128 LT=8

typedef unsigned short u16;
typedef float f32x4 __attribute__((ext_vector_type(4)));
typedef short bf16x8 __attribute__((ext_vector_type(8)));

#define KP 320   // E=300 padded to mult of 32
#define FH 1024  // 4*H
#define HH 256   // H

static __device__ __forceinline__ u16 f2bf(float f) {
    unsigned int u = __float_as_uint(f);
    u += 0x7FFFu + ((u >> 16) & 1u);          // RNE
    return (u16)(u >> 16);
}
static __device__ __forceinline__ float bf2f(u16 s) {
    return __uint_as_float((unsigned int)s << 16);
}
static __device__ __forceinline__ float sigm(float x) {
    return __builtin_amdgcn_rcpf(1.0f + __expf(-x));
}
static __device__ __forceinline__ float tanh_(float x) {
    return 1.0f - 2.0f * __builtin_amdgcn_rcpf(1.0f + __expf(2.0f * x));
}

// ---------------------------------------------------------------- embedding
// rows 0..16383 -> sentence [b*128+t], rows 16384..17407 -> target [b*8+t]
__global__ void embed_kernel(const int* __restrict__ sen, const int* __restrict__ tgt,
                             const float* __restrict__ emb,
                             u16* __restrict__ Xs, u16* __restrict__ Xt)
{
    int row = blockIdx.x;
    int tok; u16* dst;
    if (row < 16384) { tok = sen[row]; dst = Xs + (size_t)row * KP; }
    else             { tok = tgt[row - 16384]; dst = Xt + (size_t)(row - 16384) * KP; }
    const float* src = emb + (size_t)tok * 300;
    for (int k = threadIdx.x; k < KP; k += blockDim.x) {
        float v = (k < 300 && tok != 0) ? src[k] : 0.0f;   // padding_idx=0
        dst[k] = f2bf(v);
    }
}

// ---------------------------------------------------------------- weight prep (one dir)
__global__ void prep_weights_kernel(const float* __restrict__ Wih, const float* __restrict__ Whh,
                                    const float* __restrict__ bih, const float* __restrict__ bhh,
                                    u16* __restrict__ WihB, u16* __restrict__ WhhB,
                                    float* __restrict__ biasB)
{
    int idx = blockIdx.x * 256 + threadIdx.x;
    if (idx < FH * KP) {
        int row = idx / KP, k = idx - row * KP;
        WihB[idx] = (k < 300) ? f2bf(Wih[row * 300 + k]) : (u16)0;
    }
    if (idx < FH * HH) WhhB[idx] = f2bf(Whh[idx]);
    if (idx < FH)      biasB[idx] = bih[idx] + bhh[idx];
}

// ---------------------------------------------------------------- input GEMM
// G[m][n] = sum_k X[m][k] * W[n][k].  64x64 tile per WG, 4 waves (16 rows each).
// MFMA 16x16x32 bf16: A lane(m=l&15, k=quad*8+j), B lane(n=l&15, k=quad*8+j),
// D lane(col=l&15, row=quad*4+reg)  [verified layouts m89/m120]
__global__ __launch_bounds__(256) void input_gemm_kernel(
    const u16* __restrict__ X, const u16* __restrict__ W,
    u16* __restrict__ G, int M)
{
    int wave = threadIdx.x >> 6, lane = threadIdx.x & 63;
    int r = lane & 15, quad = lane >> 4;
    int m0 = blockIdx.x * 64 + wave * 16;
    int n0 = blockIdx.y * 64;
    f32x4 acc[4] = {};
    const u16* xr = X + (size_t)(m0 + r) * KP + quad * 8;
    const u16* wr = W + (size_t)(n0 + r) * KP + quad * 8;
#pragma unroll
    for (int k0 = 0; k0 < KP; k0 += 32) {
        bf16x8 a = *(const bf16x8*)(xr + k0);
#pragma unroll
        for (int j = 0; j < 4; ++j) {
            bf16x8 b = *(const bf16x8*)(wr + (size_t)j * 16 * KP + k0);
            acc[j] = __builtin_amdgcn_mfma_f32_16x16x32_bf16(a, b, acc[j], 0, 0, 0);
        }
    }
#pragma unroll
    for (int j = 0; j < 4; ++j)
#pragma unroll
        for (int reg = 0; reg < 4; ++reg) {
            int row = quad * 4 + reg;
            G[(size_t)(m0 + row) * FH + n0 + j * 16 + r] = f2bf(acc[j][reg]);
        }
}

// ---------------------------------------------------------------- LSTM scan
// 32 WGs: dir = bx>>3 (0 sf,1 sb,2 tf,3 tb), batch chunk = (bx&7)*16.
// Per step: G_pre = h @ Whh^T (MFMA, Whh streamed from L2) + pregates + bias,
// gates -> c,h.  h double-buffered in LDS (bf16, padded pitch 264 => 2-way
// bank alias only). c lives in VGPRs. One __syncthreads per step.
__global__ __launch_bounds__(256) void lstm_scan_kernel(
    const u16* __restrict__ WhhB,   // [4][1024][256] bf16
    const u16* __restrict__ Gs,     // [2][16384][1024] bf16
    const u16* __restrict__ Gt,     // [2][1024][1024] bf16
    const float* __restrict__ biasB,// [4][1024]
    float* __restrict__ senH,       // [128][128][512]
    float* __restrict__ tgtH)       // [128][8][512]
{
    const int bx  = blockIdx.x;
    const int dir = bx >> 3;
    const int b0  = (bx & 7) << 4;
    const int T   = (dir < 2) ? 128 : 8;
    const int rev = dir & 1;
    const u16* Whh  = WhhB + (size_t)dir * FH * HH;
    const u16* G    = (dir < 2) ? (Gs + (size_t)dir * 16384 * FH)
                                : (Gt + (size_t)(dir - 2) * 1024 * FH);
    const float* bias = biasB + dir * FH;
    float* Hout = (dir < 2) ? senH : tgtH;
    const int hofs = rev ? 256 : 0;

    const int tid = threadIdx.x;
    const int wave = tid >> 6, lane = tid & 63;
    const int r = lane & 15, quad = lane >> 4;

    __shared__ u16 hbuf[2][16][264];
    {
        u16* hz = &hbuf[0][0][0];
        for (int i = tid; i < 2 * 16 * 264; i += 256) hz[i] = 0;
    }
    __syncthreads();

    // wave owns hidden units [wave*64, wave*64+64); 16 n-tiles = {g*256+wave*64+j*16}
    int   woff[16];   // Whh element offset of this lane's B-frag base
    float bb[16];
    int   ncol[16];
#pragma unroll
    for (int g = 0; g < 4; ++g)
#pragma unroll
        for (int j = 0; j < 4; ++j) {
            int n = g * 256 + wave * 64 + j * 16 + r;
            woff[g * 4 + j] = n * HH + quad * 8;
            bb[g * 4 + j]   = bias[n];
            ncol[g * 4 + j] = n;
        }
    float c[4][4] = {};  // [j][reg]

    int cur = 0;
    for (int s = 0; s < T; ++s) {
        const int t = rev ? (T - 1 - s) : s;
        f32x4 acc[16] = {};
#pragma unroll
        for (int kt = 0; kt < 8; ++kt) {
            bf16x8 a = *(const bf16x8*)(&hbuf[cur][r][kt * 32 + quad * 8]);
#pragma unroll
            for (int i = 0; i < 16; ++i) {
                bf16x8 b = *(const bf16x8*)(Whh + woff[i] + kt * 32);
                acc[i] = __builtin_amdgcn_mfma_f32_16x16x32_bf16(a, b, acc[i], 0, 0, 0);
            }
        }
#pragma unroll
        for (int j = 0; j < 4; ++j)
#pragma unroll
            for (int reg = 0; reg < 4; ++reg) {
                int row = quad * 4 + reg;
                size_t gbase = ((size_t)(b0 + row) * T + t) * FH;
                float pi = acc[0 * 4 + j][reg] + bf2f(G[gbase + ncol[0 * 4 + j]]) + bb[0 * 4 + j];
                float pf = acc[1 * 4 + j][reg] + bf2f(G[gbase + ncol[1 * 4 + j]]) + bb[1 * 4 + j];
                float pg = acc[2 * 4 + j][reg] + bf2f(G[gbase + ncol[2 * 4 + j]]) + bb[2 * 4 + j];
                float po = acc[3 * 4 + j][reg] + bf2f(G[gbase + ncol[3 * 4 + j]]) + bb[3 * 4 + j];
                float ig = sigm(pi), fg = sigm(pf), gg = tanh_(pg), og = sigm(po);
                float cn = fg * c[j][reg] + ig * gg;
                c[j][reg] = cn;
                float hn = og * tanh_(cn);
                int hcol = wave * 64 + j * 16 + r;
                hbuf[cur ^ 1][row][hcol] = f2bf(hn);
                Hout[((size_t)(b0 + row) * T + t) * 512 + hofs + hcol] = hn;
            }
        __syncthreads();
        cur ^= 1;
    }
}

// ---------------------------------------------------------------- attention + head
// one WG (256 thr) per batch element
__global__ __launch_bounds__(256) void attn_out_kernel(
    const float* __restrict__ senH, const float* __restrict__ tgtH,
    const float* __restrict__ Wout, const float* __restrict__ bout,
    float* __restrict__ out)
{
    int b = blockIdx.x, tid = threadIdx.x;
    __shared__ float tg[8][512];
    __shared__ float Am[128][9];
    __shared__ float rowm[128][9];
    __shared__ float mcol[8], csum[8], rvec[8], attn[128], score[512], lg[3];

    const float* tgg = tgtH + (size_t)b * 8 * 512;
    for (int i = tid; i < 4096; i += 256) tg[i >> 9][i & 511] = tgg[i];
    __syncthreads();

    {   // A[s][t] = sen_h[b,s,:] . tgt_h[b,t,:]
        int s = tid >> 1, t0 = (tid & 1) * 4;
        const float* sr = senH + ((size_t)b * 128 + s) * 512;
        float d0 = 0, d1 = 0, d2 = 0, d3 = 0;
        for (int h = 0; h < 512; ++h) {
            float x = sr[h];
            d0 += x * tg[t0 + 0][h]; d1 += x * tg[t0 + 1][h];
            d2 += x * tg[t0 + 2][h]; d3 += x * tg[t0 + 3][h];
        }
        Am[s][t0 + 0] = d0; Am[s][t0 + 1] = d1; Am[s][t0 + 2] = d2; Am[s][t0 + 3] = d3;
    }
    __syncthreads();

    if (tid < 8) {  // col-softmax stats over s, per t
        float m = -1e30f;
        for (int s = 0; s < 128; ++s) m = fmaxf(m, Am[s][tid]);
        float sum = 0;
        for (int s = 0; s < 128; ++s) sum += __expf(Am[s][tid] - m);
        mcol[tid] = m; csum[tid] = sum;
    }
    if (tid >= 64 && tid < 192) {  // row softmax per s
        int s = tid - 64;
        float m = -1e30f;
        for (int t = 0; t < 8; ++t) m = fmaxf(m, Am[s][t]);
        float e[8], sum = 0;
        for (int t = 0; t < 8; ++t) { e[t] = __expf(Am[s][t] - m); sum += e[t]; }
        float inv = __builtin_amdgcn_rcpf(sum);
        for (int t = 0; t < 8; ++t) rowm[s][t] = e[t] * inv;
    }
    __syncthreads();
    if (tid < 8) {  // row_vec = mean over s
        float sum = 0;
        for (int s = 0; s < 128; ++s) sum += rowm[s][tid];
        rvec[tid] = sum * (1.0f / 128.0f);
    }
    __syncthreads();
    if (tid < 128) {  // attn[s] = sum_t col[s][t] * rvec[t]
        float a = 0;
        for (int t = 0; t < 8; ++t)
            a += __expf(Am[tid][t] - mcol[t]) / csum[t] * rvec[t];
        attn[tid] = a;
    }
    __syncthreads();
    for (int h = tid; h < 512; h += 256) {  // score[h] = sum_s attn[s]*sen_h[b,s,h]
        float acc = 0;
        const float* sp = senH + (size_t)b * 128 * 512 + h;
        for (int s = 0; s < 128; ++s) acc += attn[s] * sp[(size_t)s * 512];
        score[h] = acc;
    }
    __syncthreads();
    if (tid < 3) {
        float acc = bout[tid];
        const float* wr = Wout + tid * 512;
        for (int h = 0; h < 512; ++h) acc += score[h] * wr[h];
        lg[tid] = acc;
    }
    __syncthreads();
    if (tid == 0) {
        float m = fmaxf(lg[0], fmaxf(lg[1], lg[2]));
        float e0 = __expf(lg[0] - m), e1 = __expf(lg[1] - m), e2 = __expf(lg[2] - m);
        float inv = 1.0f / (e0 + e1 + e2);
        out[b * 3 + 0] = e0 * inv; out[b * 3 + 1] = e1 * inv; out[b * 3 + 2] = e2 * inv;
    }
}

// ---------------------------------------------------------------- launch
extern "C" void kernel_launch(void* const* d_in, const int* in_sizes, int n_in,
                              void* d_out, int out_size, void* d_ws, size_t ws_size,
                              hipStream_t stream)
{
    const int*   sen = (const int*)d_in[0];
    const int*   tgt = (const int*)d_in[1];
    const float* emb = (const float*)d_in[2];
    const float* Wih[4] = {(const float*)d_in[3],  (const float*)d_in[7],
                           (const float*)d_in[11], (const float*)d_in[15]};
    const float* Whh[4] = {(const float*)d_in[4],  (const float*)d_in[8],
                           (const float*)d_in[12], (const float*)d_in[16]};
    const float* bih[4] = {(const float*)d_in[5],  (const float*)d_in[9],
                           (const float*)d_in[13], (const float*)d_in[17]};
    const float* bhh[4] = {(const float*)d_in[6],  (const float*)d_in[10],
                           (const float*)d_in[14], (const float*)d_in[18]};
    const float* Wout = (const float*)d_in[19];
    const float* bout = (const float*)d_in[20];
    float* out = (float*)d_out;

    char* ws = (char*)d_ws;
    size_t off = 0;
    auto alloc = [&](size_t bytes) -> void* {
        void* p = ws + off; off += (bytes + 255) & ~(size_t)255; return p;
    };
    u16*   Xs    = (u16*)alloc((size_t)16384 * KP * 2);   // sentence emb bf16 (padded K)
    u16*   Xt    = (u16*)alloc((size_t)1024 * KP * 2);    // target emb bf16
    u16*   WihB  = (u16*)alloc((size_t)4 * FH * KP * 2);  // padded bf16 Wih
    u16*   WhhB  = (u16*)alloc((size_t)4 * FH * HH * 2);  // bf16 Whh
    float* biasB = (float*)alloc((size_t)4 * FH * 4);     // bih+bhh
    u16*   Gs    = (u16*)alloc((size_t)2 * 16384 * FH * 2); // sentence pregates bf16
    u16*   Gt    = (u16*)alloc((size_t)2 * 1024 * FH * 2);  // target pregates bf16
    float* senH  = (float*)alloc((size_t)128 * 128 * 512 * 4);
    float* tgtH  = (float*)alloc((size_t)128 * 8 * 512 * 4);
    (void)ws_size; (void)in_sizes; (void)n_in; (void)out_size;

    embed_kernel<<<17408, 128, 0, stream>>>(sen, tgt, emb, Xs, Xt);
    for (int d = 0; d < 4; ++d)
        prep_weights_kernel<<<1280, 256, 0, stream>>>(
            Wih[d], Whh[d], bih[d], bhh[d],
            WihB + (size_t)d * FH * KP, WhhB + (size_t)d * FH * HH,
            biasB + (size_t)d * FH);

    dim3 gsen(256, 16), gtgt(16, 16);
    input_gemm_kernel<<<gsen, 256, 0, stream>>>(Xs, WihB + (size_t)0 * FH * KP, Gs, 16384);
    input_gemm_kernel<<<gsen, 256, 0, stream>>>(Xs, WihB + (size_t)1 * FH * KP,
                                                Gs + (size_t)16384 * FH, 16384);
    input_gemm_kernel<<<gtgt, 256, 0, stream>>>(Xt, WihB + (size_t)2 * FH * KP, Gt, 1024);
    input_gemm_kernel<<<gtgt, 256, 0, stream>>>(Xt, WihB + (size_t)3 * FH * KP,
                                                Gt + (size_t)1024 * FH, 1024);

    lstm_scan_kernel<<<32, 256, 0, stream>>>(WhhB, Gs, Gt, biasB, senH, tgtH);
    attn_out_kernel<<<128, 256, 0, stream>>>(senH, tgtH, Wout, bout, out);
}

// Round 3
// 1893.071 us; speedup vs baseline: 1.2049x; 1.2049x over previous
//
#include <hip/hip_runtime.h>

// Encoder: embed -> 4x input GEMM (bf16 MFMA, bias folded, gate-interleaved out)
//          -> 4x LSTM scan (N-split gangs, register-resident Whh, flag sync)
//          -> co-attention + output head.
// Sizes: V=100000 E=300 H=256 OUT=3 B=128 LS=128 LT=8

typedef unsigned short u16;
typedef unsigned long long u64;
typedef float f32x4 __attribute__((ext_vector_type(4)));
typedef short bf16x8 __attribute__((ext_vector_type(8)));
typedef short s16x4 __attribute__((ext_vector_type(4)));

#define KP 320   // E=300 padded to mult of 32
#define FH 1024  // 4*H
#define HH 256   // H

static __device__ __forceinline__ u16 f2bf(float f) {
    unsigned int u = __float_as_uint(f);
    u += 0x7FFFu + ((u >> 16) & 1u);          // RNE
    return (u16)(u >> 16);
}
static __device__ __forceinline__ float bf2f(u16 s) {
    return __uint_as_float((unsigned int)s << 16);
}
static __device__ __forceinline__ float sigm(float x) {
    return __builtin_amdgcn_rcpf(1.0f + __expf(-x));
}
static __device__ __forceinline__ float tanh_(float x) {
    return 1.0f - 2.0f * __builtin_amdgcn_rcpf(1.0f + __expf(2.0f * x));
}

// ---------------------------------------------------------------- embedding
__global__ void embed_kernel(const int* __restrict__ sen, const int* __restrict__ tgt,
                             const float* __restrict__ emb,
                             u16* __restrict__ Xs, u16* __restrict__ Xt)
{
    int row = blockIdx.x;
    int tok; u16* dst;
    if (row < 16384) { tok = sen[row]; dst = Xs + (size_t)row * KP; }
    else             { tok = tgt[row - 16384]; dst = Xt + (size_t)(row - 16384) * KP; }
    const float* src = emb + (size_t)tok * 300;
    for (int k = threadIdx.x; k < KP; k += blockDim.x) {
        float v = (k < 300 && tok != 0) ? src[k] : 0.0f;   // padding_idx=0
        dst[k] = f2bf(v);
    }
}

// ---------------------------------------------------------------- weight prep (one dir)
__global__ void prep_weights_kernel(const float* __restrict__ Wih, const float* __restrict__ Whh,
                                    const float* __restrict__ bih, const float* __restrict__ bhh,
                                    u16* __restrict__ WihB, u16* __restrict__ WhhB,
                                    float* __restrict__ biasB)
{
    int idx = blockIdx.x * 256 + threadIdx.x;
    if (idx < FH * KP) {
        int row = idx / KP, k = idx - row * KP;
        WihB[idx] = (k < 300) ? f2bf(Wih[row * 300 + k]) : (u16)0;
    }
    if (idx < FH * HH) WhhB[idx] = f2bf(Whh[idx]);
    if (idx < FH)      biasB[idx] = bih[idx] + bhh[idx];
}

// ---------------------------------------------------------------- input GEMM
// G layout out: [row m][unit*4 + gate] bf16, bias folded in.
// MFMA 16x16x32 bf16: A lane(m=l&15,k=quad*8+j), B lane(n=l&15,k=quad*8+j),
// D lane(col(n)=l&15, row(m)=quad*4+reg)
__global__ __launch_bounds__(256) void input_gemm_kernel(
    const u16* __restrict__ X, const u16* __restrict__ W,
    const float* __restrict__ bias, u16* __restrict__ G, int M)
{
    int wave = threadIdx.x >> 6, lane = threadIdx.x & 63;
    int r = lane & 15, quad = lane >> 4;
    int m0 = blockIdx.x * 64 + wave * 16;
    int n0 = blockIdx.y * 64;
    f32x4 acc[4] = {};
    const u16* xr = X + (size_t)(m0 + r) * KP + quad * 8;
    const u16* wr = W + (size_t)(n0 + r) * KP + quad * 8;
#pragma unroll
    for (int k0 = 0; k0 < KP; k0 += 32) {
        bf16x8 a = *(const bf16x8*)(xr + k0);
#pragma unroll
        for (int j = 0; j < 4; ++j) {
            bf16x8 b = *(const bf16x8*)(wr + (size_t)j * 16 * KP + k0);
            acc[j] = __builtin_amdgcn_mfma_f32_16x16x32_bf16(a, b, acc[j], 0, 0, 0);
        }
    }
#pragma unroll
    for (int j = 0; j < 4; ++j)
#pragma unroll
        for (int reg = 0; reg < 4; ++reg) {
            int row = quad * 4 + reg;
            int n = n0 + j * 16 + r;
            int gate = n >> 8, unit = n & 255;
            G[(size_t)(m0 + row) * FH + unit * 4 + gate] = f2bf(acc[j][reg] + bias[n]);
        }
}

// ---------------------------------------------------------------- LSTM scan
// 32 WGs. bx = nchunk*8 + dir*2 + bchunk  (gang members share bx%8 -> same-XCD
// heuristic; correctness is via agent-scope atomics, not placement).
// Gang = (dir, bchunk of 64 batches); members nchunk=0..3 each own 64 hidden
// units (x4 gates = 256 Whh rows, held in REGISTERS as MFMA B-frags).
// Per step: prefetch G (h-independent) -> spin on gang flag -> stage h chunk
// (32KB) to LDS via agent atomic loads -> 128 MFMA/wave -> gates -> write h
// slice via agent atomic stores -> fence -> release flag add.
// Flag gating also prevents the double-buffer WAR: reaching step s+1's writes
// requires all members' step-s release, which follows their step-s reads.
__global__ __launch_bounds__(256, 1) void lstm_scan_kernel(
    const u16* __restrict__ WhhB,   // [4][1024][256] bf16
    const u16* __restrict__ Gs,     // [2][16384][1024] bf16 (gate-interleaved)
    const u16* __restrict__ Gt,     // [2][1024][1024] bf16
    float* __restrict__ senH,       // [128][128][512]
    float* __restrict__ tgtH,       // [128][8][512]
    u16* __restrict__ hglob,        // [4][2][2][64][256] bf16 (dir,bchunk,buf,b,unit)
    unsigned int* __restrict__ flags) // [8 gangs] * 16 ints padding
{
    const int bx     = blockIdx.x;
    const int nchunk = bx >> 3;
    const int dir    = (bx >> 1) & 3;
    const int bchunk = bx & 1;
    const int T      = (dir < 2) ? 128 : 8;
    const int rev    = dir & 1;
    const int b0     = bchunk * 64;

    const u16* Whh = WhhB + (size_t)dir * FH * HH;
    const u16* G   = (dir < 2) ? (Gs + (size_t)dir * 16384 * FH)
                               : (Gt + (size_t)(dir - 2) * 1024 * FH);
    float* Hout = (dir < 2) ? senH : tgtH;
    const int hofs = rev ? 256 : 0;

    u16* hg = hglob + (size_t)(dir * 2 + bchunk) * 2 * 64 * 256;  // [buf][64][256]
    unsigned int* flagp = flags + (dir * 2 + bchunk) * 16;

    const int tid  = threadIdx.x;
    const int wave = tid >> 6, lane = tid & 63;
    const int r = lane & 15, quad = lane >> 4;
    const int u0w = nchunk * 64 + wave * 16 + r;   // this lane's hidden unit

    __shared__ u16 hstage[64][264];                // padded pitch: 2-way alias only

    // ---- load Whh B-fragments into registers (persist across all steps)
    bf16x8 Bf[4][8];
#pragma unroll
    for (int g = 0; g < 4; ++g)
#pragma unroll
        for (int kt = 0; kt < 8; ++kt)
            Bf[g][kt] = *(const bf16x8*)(Whh + (size_t)(g * 256 + u0w) * HH + kt * 32 + quad * 8);

    float c[4][4] = {};   // [m][reg] cell state

    for (int s = 0; s < T; ++s) {
        const int t = rev ? (T - 1 - s) : s;

        // ---- prefetch pregates (independent of h) : 4 gates per (batch,unit)
        s16x4 gv[4][4];
#pragma unroll
        for (int m = 0; m < 4; ++m)
#pragma unroll
            for (int reg = 0; reg < 4; ++reg) {
                int bglob = b0 + m * 16 + quad * 4 + reg;
                gv[m][reg] = *(const s16x4*)(G + ((size_t)bglob * T + t) * FH + u0w * 4);
            }

        // ---- wait for all gang members to have produced h of step s-1
        if (s > 0) {
            if (tid == 0) {
                unsigned int target = 4u * (unsigned int)s;
                while (__hip_atomic_load(flagp, __ATOMIC_ACQUIRE, __HIP_MEMORY_SCOPE_AGENT) < target) {}
            }
        }
        __syncthreads();

        // ---- stage h chunk [64][256] bf16 from global (coherent loads) to LDS
        // 4096 u64 words total; 64 u64 per batch row (256 bf16 = 512 B).
        {
            const u64* src = (const u64*)(hg + (size_t)(s & 1) * 64 * 256);
#pragma unroll
            for (int i = 0; i < 16; ++i) {
                int f = i * 256 + tid;             // 4096 u64 words
                u64 v = __hip_atomic_load(src + f, __ATOMIC_RELAXED, __HIP_MEMORY_SCOPE_AGENT);
                int row = f >> 6, c4 = f & 63;     // FIXED (was >>5 / &31: scrambled + LDS OOB)
                *(u64*)&hstage[row][c4 * 4] = v;
            }
        }
        __syncthreads();

        // ---- h @ Whh^T for this WG's 64 units x 4 gates, 64 batches
        f32x4 acc[4][4] = {};                       // [m][gate]
#pragma unroll
        for (int m = 0; m < 4; ++m)
#pragma unroll
            for (int kt = 0; kt < 8; ++kt) {
                bf16x8 a = *(const bf16x8*)(&hstage[m * 16 + r][kt * 32 + quad * 8]);
#pragma unroll
                for (int g = 0; g < 4; ++g)
                    acc[m][g] = __builtin_amdgcn_mfma_f32_16x16x32_bf16(a, Bf[g][kt], acc[m][g], 0, 0, 0);
            }

        // ---- gates -> c,h ; write h slice + output
        u16* hdst = hg + (size_t)((s + 1) & 1) * 64 * 256;
#pragma unroll
        for (int m = 0; m < 4; ++m)
#pragma unroll
            for (int reg = 0; reg < 4; ++reg) {
                int blocal = m * 16 + quad * 4 + reg;
                int bglob  = b0 + blocal;
                float pi = acc[m][0][reg] + bf2f((u16)gv[m][reg].x);
                float pf = acc[m][1][reg] + bf2f((u16)gv[m][reg].y);
                float pg = acc[m][2][reg] + bf2f((u16)gv[m][reg].z);
                float po = acc[m][3][reg] + bf2f((u16)gv[m][reg].w);
                float ig = sigm(pi), fg = sigm(pf), gg = tanh_(pg), og = sigm(po);
                float cn = fg * c[m][reg] + ig * gg;
                c[m][reg] = cn;
                float hn = og * tanh_(cn);
                __hip_atomic_store(&hdst[blocal * 256 + u0w], f2bf(hn),
                                   __ATOMIC_RELAXED, __HIP_MEMORY_SCOPE_AGENT);
                Hout[((size_t)bglob * T + t) * 512 + hofs + u0w] = hn;
            }

        __threadfence();
        __syncthreads();
        if (tid == 0)
            __hip_atomic_fetch_add(flagp, 1u, __ATOMIC_RELEASE, __HIP_MEMORY_SCOPE_AGENT);
    }
}

// ---------------------------------------------------------------- attention + head
__global__ __launch_bounds__(256) void attn_out_kernel(
    const float* __restrict__ senH, const float* __restrict__ tgtH,
    const float* __restrict__ Wout, const float* __restrict__ bout,
    float* __restrict__ out)
{
    int b = blockIdx.x, tid = threadIdx.x;
    __shared__ float tg[8][512];
    __shared__ float Am[128][9];
    __shared__ float rowm[128][9];
    __shared__ float mcol[8], csum[8], rvec[8], attn[128], score[512], lg[3];

    const float* tgg = tgtH + (size_t)b * 8 * 512;
    for (int i = tid; i < 4096; i += 256) tg[i >> 9][i & 511] = tgg[i];
    __syncthreads();

    {   // A[s][t] = sen_h[b,s,:] . tgt_h[b,t,:]
        int s = tid >> 1, t0 = (tid & 1) * 4;
        const float* sr = senH + ((size_t)b * 128 + s) * 512;
        float d0 = 0, d1 = 0, d2 = 0, d3 = 0;
        for (int h = 0; h < 512; ++h) {
            float x = sr[h];
            d0 += x * tg[t0 + 0][h]; d1 += x * tg[t0 + 1][h];
            d2 += x * tg[t0 + 2][h]; d3 += x * tg[t0 + 3][h];
        }
        Am[s][t0 + 0] = d0; Am[s][t0 + 1] = d1; Am[s][t0 + 2] = d2; Am[s][t0 + 3] = d3;
    }
    __syncthreads();

    if (tid < 8) {  // col-softmax stats over s, per t
        float m = -1e30f;
        for (int s = 0; s < 128; ++s) m = fmaxf(m, Am[s][tid]);
        float sum = 0;
        for (int s = 0; s < 128; ++s) sum += __expf(Am[s][tid] - m);
        mcol[tid] = m; csum[tid] = sum;
    }
    if (tid >= 64 && tid < 192) {  // row softmax per s
        int s = tid - 64;
        float m = -1e30f;
        for (int t = 0; t < 8; ++t) m = fmaxf(m, Am[s][t]);
        float e[8], sum = 0;
        for (int t = 0; t < 8; ++t) { e[t] = __expf(Am[s][t] - m); sum += e[t]; }
        float inv = __builtin_amdgcn_rcpf(sum);
        for (int t = 0; t < 8; ++t) rowm[s][t] = e[t] * inv;
    }
    __syncthreads();
    if (tid < 8) {
        float sum = 0;
        for (int s = 0; s < 128; ++s) sum += rowm[s][tid];
        rvec[tid] = sum * (1.0f / 128.0f);
    }
    __syncthreads();
    if (tid < 128) {
        float a = 0;
        for (int t = 0; t < 8; ++t)
            a += __expf(Am[tid][t] - mcol[t]) / csum[t] * rvec[t];
        attn[tid] = a;
    }
    __syncthreads();
    for (int h = tid; h < 512; h += 256) {
        float acc = 0;
        const float* sp = senH + (size_t)b * 128 * 512 + h;
        for (int s = 0; s < 128; ++s) acc += attn[s] * sp[(size_t)s * 512];
        score[h] = acc;
    }
    __syncthreads();
    if (tid < 3) {
        float acc = bout[tid];
        const float* wr = Wout + tid * 512;
        for (int h = 0; h < 512; ++h) acc += score[h] * wr[h];
        lg[tid] = acc;
    }
    __syncthreads();
    if (tid == 0) {
        float m = fmaxf(lg[0], fmaxf(lg[1], lg[2]));
        float e0 = __expf(lg[0] - m), e1 = __expf(lg[1] - m), e2 = __expf(lg[2] - m);
        float inv = 1.0f / (e0 + e1 + e2);
        out[b * 3 + 0] = e0 * inv; out[b * 3 + 1] = e1 * inv; out[b * 3 + 2] = e2 * inv;
    }
}

// ---------------------------------------------------------------- launch
extern "C" void kernel_launch(void* const* d_in, const int* in_sizes, int n_in,
                              void* d_out, int out_size, void* d_ws, size_t ws_size,
                              hipStream_t stream)
{
    const int*   sen = (const int*)d_in[0];
    const int*   tgt = (const int*)d_in[1];
    const float* emb = (const float*)d_in[2];
    const float* Wih[4] = {(const float*)d_in[3],  (const float*)d_in[7],
                           (const float*)d_in[11], (const float*)d_in[15]};
    const float* Whh[4] = {(const float*)d_in[4],  (const float*)d_in[8],
                           (const float*)d_in[12], (const float*)d_in[16]};
    const float* bih[4] = {(const float*)d_in[5],  (const float*)d_in[9],
                           (const float*)d_in[13], (const float*)d_in[17]};
    const float* bhh[4] = {(const float*)d_in[6],  (const float*)d_in[10],
                           (const float*)d_in[14], (const float*)d_in[18]};
    const float* Wout = (const float*)d_in[19];
    const float* bout = (const float*)d_in[20];
    float* out = (float*)d_out;

    char* ws = (char*)d_ws;
    size_t off = 0;
    auto alloc = [&](size_t bytes) -> void* {
        void* p = ws + off; off += (bytes + 255) & ~(size_t)255; return p;
    };
    u16*   Xs    = (u16*)alloc((size_t)16384 * KP * 2);
    u16*   Xt    = (u16*)alloc((size_t)1024 * KP * 2);
    u16*   WihB  = (u16*)alloc((size_t)4 * FH * KP * 2);
    u16*   WhhB  = (u16*)alloc((size_t)4 * FH * HH * 2);
    float* biasB = (float*)alloc((size_t)4 * FH * 4);
    u16*   Gs    = (u16*)alloc((size_t)2 * 16384 * FH * 2);
    u16*   Gt    = (u16*)alloc((size_t)2 * 1024 * FH * 2);
    float* senH  = (float*)alloc((size_t)128 * 128 * 512 * 4);
    float* tgtH  = (float*)alloc((size_t)128 * 8 * 512 * 4);
    u16*   hglob = (u16*)alloc((size_t)4 * 2 * 2 * 64 * 256 * 2);  // 512 KB
    unsigned int* flags = (unsigned int*)alloc(8 * 16 * 4);        // adjacent to hglob
    (void)ws_size; (void)in_sizes; (void)n_in; (void)out_size;

    // zero h double-buffers (h0 = 0) and gang flags (ws is poisoned 0xAA)
    hipMemsetAsync(hglob, 0, (size_t)4 * 2 * 2 * 64 * 256 * 2 + 8 * 16 * 4, stream);

    embed_kernel<<<17408, 128, 0, stream>>>(sen, tgt, emb, Xs, Xt);
    for (int d = 0; d < 4; ++d)
        prep_weights_kernel<<<1280, 256, 0, stream>>>(
            Wih[d], Whh[d], bih[d], bhh[d],
            WihB + (size_t)d * FH * KP, WhhB + (size_t)d * FH * HH,
            biasB + (size_t)d * FH);

    dim3 gsen(256, 16), gtgt(16, 16);
    input_gemm_kernel<<<gsen, 256, 0, stream>>>(Xs, WihB + (size_t)0 * FH * KP,
                                                biasB + 0 * FH, Gs, 16384);
    input_gemm_kernel<<<gsen, 256, 0, stream>>>(Xs, WihB + (size_t)1 * FH * KP,
                                                biasB + 1 * FH, Gs + (size_t)16384 * FH, 16384);
    input_gemm_kernel<<<gtgt, 256, 0, stream>>>(Xt, WihB + (size_t)2 * FH * KP,
                                                biasB + 2 * FH, Gt, 1024);
    input_gemm_kernel<<<gtgt, 256, 0, stream>>>(Xt, WihB + (size_t)3 * FH * KP,
                                                biasB + 3 * FH, Gt + (size_t)1024 * FH, 1024);

    lstm_scan_kernel<<<32, 256, 0, stream>>>(WhhB, Gs, Gt, senH, tgtH, hglob, flags);
    attn_out_kernel<<<128, 256, 0, stream>>>(senH, tgtH, Wout, bout, out);
}

// Round 4
// 1493.365 us; speedup vs baseline: 1.5274x; 1.2677x over previous
//
#include <hip/hip_runtime.h>

// Encoder: embed -> 4x input GEMM (bf16 MFMA, bias folded, gate-interleaved out)
//          -> 4x LSTM scan (N-split gangs, register-resident Whh, fence-free
//             flag sync via sc-flagged (IC-coherent) relaxed atomics)
//          -> co-attention + output head.
// Sizes: V=100000 E=300 H=256 OUT=3 B=128 LS=128 LT=8

typedef unsigned short u16;
typedef unsigned long long u64;
typedef float f32x4 __attribute__((ext_vector_type(4)));
typedef short bf16x8 __attribute__((ext_vector_type(8)));
typedef short s16x4 __attribute__((ext_vector_type(4)));

#define KP 320   // E=300 padded to mult of 32
#define FH 1024  // 4*H
#define HH 256   // H

static __device__ __forceinline__ u16 f2bf(float f) {
    unsigned int u = __float_as_uint(f);
    u += 0x7FFFu + ((u >> 16) & 1u);          // RNE
    return (u16)(u >> 16);
}
static __device__ __forceinline__ float bf2f(u16 s) {
    return __uint_as_float((unsigned int)s << 16);
}
static __device__ __forceinline__ float sigm(float x) {
    return __builtin_amdgcn_rcpf(1.0f + __expf(-x));
}
static __device__ __forceinline__ float tanh_(float x) {
    return 1.0f - 2.0f * __builtin_amdgcn_rcpf(1.0f + __expf(2.0f * x));
}

// ---------------------------------------------------------------- embedding
__global__ void embed_kernel(const int* __restrict__ sen, const int* __restrict__ tgt,
                             const float* __restrict__ emb,
                             u16* __restrict__ Xs, u16* __restrict__ Xt)
{
    int row = blockIdx.x;
    int tok; u16* dst;
    if (row < 16384) { tok = sen[row]; dst = Xs + (size_t)row * KP; }
    else             { tok = tgt[row - 16384]; dst = Xt + (size_t)(row - 16384) * KP; }
    const float* src = emb + (size_t)tok * 300;
    for (int k = threadIdx.x; k < KP; k += blockDim.x) {
        float v = (k < 300 && tok != 0) ? src[k] : 0.0f;   // padding_idx=0
        dst[k] = f2bf(v);
    }
}

// ---------------------------------------------------------------- weight prep (one dir)
__global__ void prep_weights_kernel(const float* __restrict__ Wih, const float* __restrict__ Whh,
                                    const float* __restrict__ bih, const float* __restrict__ bhh,
                                    u16* __restrict__ WihB, u16* __restrict__ WhhB,
                                    float* __restrict__ biasB)
{
    int idx = blockIdx.x * 256 + threadIdx.x;
    if (idx < FH * KP) {
        int row = idx / KP, k = idx - row * KP;
        WihB[idx] = (k < 300) ? f2bf(Wih[row * 300 + k]) : (u16)0;
    }
    if (idx < FH * HH) WhhB[idx] = f2bf(Whh[idx]);
    if (idx < FH)      biasB[idx] = bih[idx] + bhh[idx];
}

// ---------------------------------------------------------------- input GEMM
// G layout out: [row m][unit*4 + gate] bf16, bias folded in.
__global__ __launch_bounds__(256) void input_gemm_kernel(
    const u16* __restrict__ X, const u16* __restrict__ W,
    const float* __restrict__ bias, u16* __restrict__ G, int M)
{
    int wave = threadIdx.x >> 6, lane = threadIdx.x & 63;
    int r = lane & 15, quad = lane >> 4;
    int m0 = blockIdx.x * 64 + wave * 16;
    int n0 = blockIdx.y * 64;
    f32x4 acc[4] = {};
    const u16* xr = X + (size_t)(m0 + r) * KP + quad * 8;
    const u16* wr = W + (size_t)(n0 + r) * KP + quad * 8;
#pragma unroll
    for (int k0 = 0; k0 < KP; k0 += 32) {
        bf16x8 a = *(const bf16x8*)(xr + k0);
#pragma unroll
        for (int j = 0; j < 4; ++j) {
            bf16x8 b = *(const bf16x8*)(wr + (size_t)j * 16 * KP + k0);
            acc[j] = __builtin_amdgcn_mfma_f32_16x16x32_bf16(a, b, acc[j], 0, 0, 0);
        }
    }
#pragma unroll
    for (int j = 0; j < 4; ++j)
#pragma unroll
        for (int reg = 0; reg < 4; ++reg) {
            int row = quad * 4 + reg;
            int n = n0 + j * 16 + r;
            int gate = n >> 8, unit = n & 255;
            G[(size_t)(m0 + row) * FH + unit * 4 + gate] = f2bf(acc[j][reg] + bias[n]);
        }
}

// ---------------------------------------------------------------- LSTM scan
// 32 WGs. bx = nchunk*8 + dir*2 + bchunk. Gang = (dir, bchunk of 64 batches);
// members nchunk=0..3 each own 64 hidden units (Whh rows in REGISTERS).
// FENCE-FREE sync: all data exchange + flags use sc-flagged relaxed agent
// atomics, which read/write through to the Infinity Cache (the cross-XCD
// coherence point). Release = per-wave s_waitcnt vmcnt(0) (stores acked at
// IC) -> barrier -> relaxed fetch_add. Spin = relaxed load (NO buffer_inv:
// R3's ACQUIRE spin invalidated L2 every poll -> 11.4us/step handoff).
// Flag gating also prevents the double-buffer WAR: reaching step s+1's
// writes requires all members' step-s release, after their step-s reads.
__global__ __launch_bounds__(256, 1) void lstm_scan_kernel(
    const u16* __restrict__ WhhB,   // [4][1024][256] bf16
    const u16* __restrict__ Gs,     // [2][16384][1024] bf16 (gate-interleaved)
    const u16* __restrict__ Gt,     // [2][1024][1024] bf16
    float* __restrict__ senH,       // [128][128][512]
    float* __restrict__ tgtH,       // [128][8][512]
    u16* __restrict__ hglob,        // [4][2][2][64][256] bf16 (dir,bchunk,buf,b,unit)
    unsigned int* __restrict__ flags) // [8 gangs] * 16 ints padding
{
    const int bx     = blockIdx.x;
    const int nchunk = bx >> 3;
    const int dir    = (bx >> 1) & 3;
    const int bchunk = bx & 1;
    const int T      = (dir < 2) ? 128 : 8;
    const int rev    = dir & 1;
    const int b0     = bchunk * 64;

    const u16* Whh = WhhB + (size_t)dir * FH * HH;
    const u16* G   = (dir < 2) ? (Gs + (size_t)dir * 16384 * FH)
                               : (Gt + (size_t)(dir - 2) * 1024 * FH);
    float* Hout = (dir < 2) ? senH : tgtH;
    const int hofs = rev ? 256 : 0;

    u16* hg = hglob + (size_t)(dir * 2 + bchunk) * 2 * 64 * 256;  // [buf][64][256]
    unsigned int* flagp = flags + (dir * 2 + bchunk) * 16;

    const int tid  = threadIdx.x;
    const int wave = tid >> 6, lane = tid & 63;
    const int r = lane & 15, quad = lane >> 4;
    const int u0w = nchunk * 64 + wave * 16 + r;   // this lane's hidden unit

    __shared__ u16 hstage[64][264];                // padded pitch

    // ---- load Whh B-fragments into registers (persist across all steps)
    bf16x8 Bf[4][8];
#pragma unroll
    for (int g = 0; g < 4; ++g)
#pragma unroll
        for (int kt = 0; kt < 8; ++kt)
            Bf[g][kt] = *(const bf16x8*)(Whh + (size_t)(g * 256 + u0w) * HH + kt * 32 + quad * 8);

    float c[4][4] = {};   // [m][reg] cell state

    for (int s = 0; s < T; ++s) {
        const int t = rev ? (T - 1 - s) : s;

        // ---- prefetch pregates (independent of h) : 4 gates per (batch,unit)
        s16x4 gv[4][4];
#pragma unroll
        for (int m = 0; m < 4; ++m)
#pragma unroll
            for (int reg = 0; reg < 4; ++reg) {
                int bglob = b0 + m * 16 + quad * 4 + reg;
                gv[m][reg] = *(const s16x4*)(G + ((size_t)bglob * T + t) * FH + u0w * 4);
            }

        // ---- wait for all gang members to have produced h of step s-1
        if (s > 0) {
            if (tid == 0) {
                unsigned int target = 4u * (unsigned int)s;
                while (__hip_atomic_load(flagp, __ATOMIC_RELAXED, __HIP_MEMORY_SCOPE_AGENT) < target) {}
            }
        }
        __syncthreads();

        // ---- stage h chunk [64][256] bf16 from IC (sc-flagged loads) to LDS
        // 4096 u64 words total; 64 u64 per batch row (256 bf16 = 512 B).
        {
            u64* src = (u64*)(hg + (size_t)(s & 1) * 64 * 256);
#pragma unroll
            for (int i = 0; i < 16; ++i) {
                int f = i * 256 + tid;             // 4096 u64 words
                u64 v = __hip_atomic_load(src + f, __ATOMIC_RELAXED, __HIP_MEMORY_SCOPE_AGENT);
                int row = f >> 6, c4 = f & 63;
                *(u64*)&hstage[row][c4 * 4] = v;
            }
        }
        __syncthreads();

        // ---- h @ Whh^T for this WG's 64 units x 4 gates, 64 batches
        f32x4 acc[4][4] = {};                       // [m][gate]
#pragma unroll
        for (int m = 0; m < 4; ++m)
#pragma unroll
            for (int kt = 0; kt < 8; ++kt) {
                bf16x8 a = *(const bf16x8*)(&hstage[m * 16 + r][kt * 32 + quad * 8]);
#pragma unroll
                for (int g = 0; g < 4; ++g)
                    acc[m][g] = __builtin_amdgcn_mfma_f32_16x16x32_bf16(a, Bf[g][kt], acc[m][g], 0, 0, 0);
            }

        // ---- gates -> c,h ; write h slice (write-through) + output
        u16* hdst = hg + (size_t)((s + 1) & 1) * 64 * 256;
#pragma unroll
        for (int m = 0; m < 4; ++m)
#pragma unroll
            for (int reg = 0; reg < 4; ++reg) {
                int blocal = m * 16 + quad * 4 + reg;
                int bglob  = b0 + blocal;
                float pi = acc[m][0][reg] + bf2f((u16)gv[m][reg].x);
                float pf = acc[m][1][reg] + bf2f((u16)gv[m][reg].y);
                float pg = acc[m][2][reg] + bf2f((u16)gv[m][reg].z);
                float po = acc[m][3][reg] + bf2f((u16)gv[m][reg].w);
                float ig = sigm(pi), fg = sigm(pf), gg = tanh_(pg), og = sigm(po);
                float cn = fg * c[m][reg] + ig * gg;
                c[m][reg] = cn;
                float hn = og * tanh_(cn);
                __hip_atomic_store(&hdst[blocal * 256 + u0w], f2bf(hn),
                                   __ATOMIC_RELAXED, __HIP_MEMORY_SCOPE_AGENT);
                Hout[((size_t)bglob * T + t) * 512 + hofs + u0w] = hn;
            }

        // ---- release: drain this wave's stores (acked at coherence point),
        // rendezvous all 4 waves, then one relaxed flag add. No wbl2/inv.
        asm volatile("s_waitcnt vmcnt(0)" ::: "memory");
        __syncthreads();
        if (tid == 0)
            __hip_atomic_fetch_add(flagp, 1u, __ATOMIC_RELAXED, __HIP_MEMORY_SCOPE_AGENT);
    }
}

// ---------------------------------------------------------------- attention + head
__global__ __launch_bounds__(256) void attn_out_kernel(
    const float* __restrict__ senH, const float* __restrict__ tgtH,
    const float* __restrict__ Wout, const float* __restrict__ bout,
    float* __restrict__ out)
{
    int b = blockIdx.x, tid = threadIdx.x;
    __shared__ float tg[8][512];
    __shared__ float Am[128][9];
    __shared__ float rowm[128][9];
    __shared__ float mcol[8], csum[8], rvec[8], attn[128], score[512], lg[3];

    const float* tgg = tgtH + (size_t)b * 8 * 512;
    for (int i = tid; i < 4096; i += 256) tg[i >> 9][i & 511] = tgg[i];
    __syncthreads();

    {   // A[s][t] = sen_h[b,s,:] . tgt_h[b,t,:]
        int s = tid >> 1, t0 = (tid & 1) * 4;
        const float* sr = senH + ((size_t)b * 128 + s) * 512;
        float d0 = 0, d1 = 0, d2 = 0, d3 = 0;
        for (int h = 0; h < 512; ++h) {
            float x = sr[h];
            d0 += x * tg[t0 + 0][h]; d1 += x * tg[t0 + 1][h];
            d2 += x * tg[t0 + 2][h]; d3 += x * tg[t0 + 3][h];
        }
        Am[s][t0 + 0] = d0; Am[s][t0 + 1] = d1; Am[s][t0 + 2] = d2; Am[s][t0 + 3] = d3;
    }
    __syncthreads();

    if (tid < 8) {  // col-softmax stats over s, per t
        float m = -1e30f;
        for (int s = 0; s < 128; ++s) m = fmaxf(m, Am[s][tid]);
        float sum = 0;
        for (int s = 0; s < 128; ++s) sum += __expf(Am[s][tid] - m);
        mcol[tid] = m; csum[tid] = sum;
    }
    if (tid >= 64 && tid < 192) {  // row softmax per s
        int s = tid - 64;
        float m = -1e30f;
        for (int t = 0; t < 8; ++t) m = fmaxf(m, Am[s][t]);
        float e[8], sum = 0;
        for (int t = 0; t < 8; ++t) { e[t] = __expf(Am[s][t] - m); sum += e[t]; }
        float inv = __builtin_amdgcn_rcpf(sum);
        for (int t = 0; t < 8; ++t) rowm[s][t] = e[t] * inv;
    }
    __syncthreads();
    if (tid < 8) {
        float sum = 0;
        for (int s = 0; s < 128; ++s) sum += rowm[s][tid];
        rvec[tid] = sum * (1.0f / 128.0f);
    }
    __syncthreads();
    if (tid < 128) {
        float a = 0;
        for (int t = 0; t < 8; ++t)
            a += __expf(Am[tid][t] - mcol[t]) / csum[t] * rvec[t];
        attn[tid] = a;
    }
    __syncthreads();
    for (int h = tid; h < 512; h += 256) {
        float acc = 0;
        const float* sp = senH + (size_t)b * 128 * 512 + h;
        for (int s = 0; s < 128; ++s) acc += attn[s] * sp[(size_t)s * 512];
        score[h] = acc;
    }
    __syncthreads();
    if (tid < 3) {
        float acc = bout[tid];
        const float* wr = Wout + tid * 512;
        for (int h = 0; h < 512; ++h) acc += score[h] * wr[h];
        lg[tid] = acc;
    }
    __syncthreads();
    if (tid == 0) {
        float m = fmaxf(lg[0], fmaxf(lg[1], lg[2]));
        float e0 = __expf(lg[0] - m), e1 = __expf(lg[1] - m), e2 = __expf(lg[2] - m);
        float inv = 1.0f / (e0 + e1 + e2);
        out[b * 3 + 0] = e0 * inv; out[b * 3 + 1] = e1 * inv; out[b * 3 + 2] = e2 * inv;
    }
}

// ---------------------------------------------------------------- launch
extern "C" void kernel_launch(void* const* d_in, const int* in_sizes, int n_in,
                              void* d_out, int out_size, void* d_ws, size_t ws_size,
                              hipStream_t stream)
{
    const int*   sen = (const int*)d_in[0];
    const int*   tgt = (const int*)d_in[1];
    const float* emb = (const float*)d_in[2];
    const float* Wih[4] = {(const float*)d_in[3],  (const float*)d_in[7],
                           (const float*)d_in[11], (const float*)d_in[15]};
    const float* Whh[4] = {(const float*)d_in[4],  (const float*)d_in[8],
                           (const float*)d_in[12], (const float*)d_in[16]};
    const float* bih[4] = {(const float*)d_in[5],  (const float*)d_in[9],
                           (const float*)d_in[13], (const float*)d_in[17]};
    const float* bhh[4] = {(const float*)d_in[6],  (const float*)d_in[10],
                           (const float*)d_in[14], (const float*)d_in[18]};
    const float* Wout = (const float*)d_in[19];
    const float* bout = (const float*)d_in[20];
    float* out = (float*)d_out;

    char* ws = (char*)d_ws;
    size_t off = 0;
    auto alloc = [&](size_t bytes) -> void* {
        void* p = ws + off; off += (bytes + 255) & ~(size_t)255; return p;
    };
    u16*   Xs    = (u16*)alloc((size_t)16384 * KP * 2);
    u16*   Xt    = (u16*)alloc((size_t)1024 * KP * 2);
    u16*   WihB  = (u16*)alloc((size_t)4 * FH * KP * 2);
    u16*   WhhB  = (u16*)alloc((size_t)4 * FH * HH * 2);
    float* biasB = (float*)alloc((size_t)4 * FH * 4);
    u16*   Gs    = (u16*)alloc((size_t)2 * 16384 * FH * 2);
    u16*   Gt    = (u16*)alloc((size_t)2 * 1024 * FH * 2);
    float* senH  = (float*)alloc((size_t)128 * 128 * 512 * 4);
    float* tgtH  = (float*)alloc((size_t)128 * 8 * 512 * 4);
    u16*   hglob = (u16*)alloc((size_t)4 * 2 * 2 * 64 * 256 * 2);  // 512 KB
    unsigned int* flags = (unsigned int*)alloc(8 * 16 * 4);        // adjacent to hglob
    (void)ws_size; (void)in_sizes; (void)n_in; (void)out_size;

    // zero h double-buffers (h0 = 0) and gang flags (ws is poisoned 0xAA)
    hipMemsetAsync(hglob, 0, (size_t)4 * 2 * 2 * 64 * 256 * 2 + 8 * 16 * 4, stream);

    embed_kernel<<<17408, 128, 0, stream>>>(sen, tgt, emb, Xs, Xt);
    for (int d = 0; d < 4; ++d)
        prep_weights_kernel<<<1280, 256, 0, stream>>>(
            Wih[d], Whh[d], bih[d], bhh[d],
            WihB + (size_t)d * FH * KP, WhhB + (size_t)d * FH * HH,
            biasB + (size_t)d * FH);

    dim3 gsen(256, 16), gtgt(16, 16);
    input_gemm_kernel<<<gsen, 256, 0, stream>>>(Xs, WihB + (size_t)0 * FH * KP,
                                                biasB + 0 * FH, Gs, 16384);
    input_gemm_kernel<<<gsen, 256, 0, stream>>>(Xs, WihB + (size_t)1 * FH * KP,
                                                biasB + 1 * FH, Gs + (size_t)16384 * FH, 16384);
    input_gemm_kernel<<<gtgt, 256, 0, stream>>>(Xt, WihB + (size_t)2 * FH * KP,
                                                biasB + 2 * FH, Gt, 1024);
    input_gemm_kernel<<<gtgt, 256, 0, stream>>>(Xt, WihB + (size_t)3 * FH * KP,
                                                biasB + 3 * FH, Gt + (size_t)1024 * FH, 1024);

    lstm_scan_kernel<<<32, 256, 0, stream>>>(WhhB, Gs, Gt, senH, tgtH, hglob, flags);
    attn_out_kernel<<<128, 256, 0, stream>>>(senH, tgtH, Wout, bout, out);
}